// Round 1
// 375.837 us; speedup vs baseline: 1.0079x; 1.0079x over previous
//
#include <hip/hip_runtime.h>
#include <math.h>
#include <stdint.h>

#define N_ROWS 8192
#define F_DIM  256
#define K_KEEP 4096
#define JCH    512   // j-chunk length for rank kernel

// native 4-float vector (HIP float4 is a class type; nontemporal builtin
// requires a native vector/scalar)
typedef float nfloat4 __attribute__((ext_vector_type(4)));

// ---------------------------------------------------------------------------
// K1: scores. One wave per row: float4 loads, double accumulation (the
// top-K boundary gap is ~3e-4; fp64 makes our scores exact vs the numpy ref).
// Also zero-inits the rank array (ws is poisoned 0xAA every iteration).
// ---------------------------------------------------------------------------
__global__ void k_scores(const float* __restrict__ X, const float* __restrict__ p,
                         float* __restrict__ s_out, float* __restrict__ t_out,
                         int* __restrict__ rank_arr) {
    const int tid  = threadIdx.x;
    const int wv   = tid >> 6;
    const int lane = tid & 63;
    const int row  = blockIdx.x * 4 + wv;

    const int gid = blockIdx.x * 256 + tid;
    if (gid < N_ROWS) rank_arr[gid] = 0;

    const float4 pv = ((const float4*)p)[lane];
    const float4 xv = ((const float4*)(X + (size_t)row * F_DIM))[lane];

    double d  = (double)xv.x * pv.x + (double)xv.y * pv.y
              + (double)xv.z * pv.z + (double)xv.w * pv.w;
    double pp = (double)pv.x * pv.x + (double)pv.y * pv.y
              + (double)pv.z * pv.z + (double)pv.w * pv.w;

    #pragma unroll
    for (int off = 32; off > 0; off >>= 1) {
        d  += __shfl_down(d, off);
        pp += __shfl_down(pp, off);
    }
    if (lane == 0) {
        double y = d / sqrt(pp);
        s_out[row] = (float)y;
        t_out[row] = tanhf((float)y);
    }
}

// ---------------------------------------------------------------------------
// K2: stable descending rank via chunked O(N^2) count.
// rank_i = #{j : s_j > s_i} + #{j < i : s_j == s_i}  (matches jax top_k ties).
// 32 i-blocks x 16 j-chunks; LDS-cached 512-score chunk, read as float4
// (4x fewer DS ops vs scalar).
// ---------------------------------------------------------------------------
__global__ void k_rank(const float* __restrict__ s, int* __restrict__ rank_arr) {
    const int ib = blockIdx.x >> 4;
    const int jc = blockIdx.x & 15;
    __shared__ float sk[JCH];
    const int tid = threadIdx.x;

    if (tid < JCH / 4)
        ((float4*)sk)[tid] = ((const float4*)(s + jc * JCH))[tid];
    __syncthreads();

    const int   i     = ib * 256 + tid;
    const float si    = s[i];
    const int   jbase = jc * JCH;
    int cnt = 0;
    #pragma unroll 4
    for (int q = 0; q < JCH / 4; ++q) {
        const float4 v = ((const float4*)sk)[q];
        const int j0 = jbase + 4 * q;
        cnt += (v.x > si) ? 1 : 0;
        cnt += ((v.x == si) && (j0 + 0 < i)) ? 1 : 0;
        cnt += (v.y > si) ? 1 : 0;
        cnt += ((v.y == si) && (j0 + 1 < i)) ? 1 : 0;
        cnt += (v.z > si) ? 1 : 0;
        cnt += ((v.z == si) && (j0 + 2 < i)) ? 1 : 0;
        cnt += (v.w > si) ? 1 : 0;
        cnt += ((v.w == si) && (j0 + 3 < i)) ? 1 : 0;
    }
    atomicAdd(&rank_arr[i], cnt);
}

// ---------------------------------------------------------------------------
// K3: compact selected indices (rank < K) in ascending index order.
// Single block, now 1024 threads x 8 contiguous elements (was 256x32):
// 4x the latency-hiding parallelism for this serial-dependency stage.
// Exactly K_KEEP are selected (rank is a permutation of 0..N-1).
// ---------------------------------------------------------------------------
__global__ __launch_bounds__(1024) void k_compact(const int* __restrict__ rank_arr,
                                                  int* __restrict__ idx) {
    const int tid  = threadIdx.x;   // 0..1023
    const int lane = tid & 63;
    const int wv   = tid >> 6;      // 0..15

    const int4 ra0 = ((const int4*)rank_arr)[tid * 2 + 0];
    const int4 ra1 = ((const int4*)rank_arr)[tid * 2 + 1];
    int r32[8] = {ra0.x, ra0.y, ra0.z, ra0.w, ra1.x, ra1.y, ra1.z, ra1.w};

    int c = 0;
    #pragma unroll
    for (int k = 0; k < 8; ++k) c += (r32[k] < K_KEEP) ? 1 : 0;

    // wave inclusive scan
    int v = c;
    #pragma unroll
    for (int off = 1; off < 64; off <<= 1) {
        int n = __shfl_up(v, off);
        if (lane >= off) v += n;
    }
    __shared__ int wsum[16];
    if (lane == 63) wsum[wv] = v;
    __syncthreads();
    int wbase = 0;
    for (int w = 0; w < wv; ++w) wbase += wsum[w];

    int pos = wbase + v - c;
    const int base = tid * 8;
    #pragma unroll
    for (int k = 0; k < 8; ++k) {
        if (r32[k] < K_KEEP) idx[pos++] = base + k;
    }
}

// ---------------------------------------------------------------------------
// K4 (fused pool): one block per output row r. Direct L1-cached gather —
// no LDS, no barrier, no DMA drain.
//  - Kept-column density is 0.5, so every 64B line of the source row is
//    touched anyway: HBM traffic is identical to streaming the whole row,
//    but lanes of one gather instruction span only ~2KB and the .y/.z/.w
//    components re-hit the same lines in L1. Each row line is fetched once.
//  - No LDS -> occupancy is VGPR-limited (tiny kernel), giving a much
//    deeper read pipeline than the old 5-blocks/CU LDS cap, and no
//    vmcnt(0) barrier drain serializing DMA against gather.
//  - Stores are lane-contiguous float4 nontemporal (the 64MB output stream
//    must not evict A lines).
//  - X_pooled row fused in (wave 0, float4).
// ---------------------------------------------------------------------------
__global__ __launch_bounds__(256) void k_pool(const float* __restrict__ X,
                                              const float* __restrict__ A,
                                              const float* __restrict__ t,
                                              const int* __restrict__ idx,
                                              float* __restrict__ out0,
                                              float* __restrict__ out1) {
    const int tid = threadIdx.x;
    const int r   = blockIdx.x;
    const int src = idx[r];                       // uniform -> s_load

    const float* __restrict__ Arow = A + (size_t)src * N_ROWS;
    float* __restrict__ orow = out1 + (size_t)r * K_KEEP;

    // X_pooled row (256 floats) on wave 0
    const float tt = t[src];
    if (tid < 64) {
        float4 v = ((const float4*)(X + (size_t)src * F_DIM))[tid];
        nfloat4 o = {v.x * tt, v.y * tt, v.z * tt, v.w * tt};
        __builtin_nontemporal_store(o, (nfloat4*)(out0 + (size_t)r * F_DIM) + tid);
    }

    #pragma unroll
    for (int k = 0; k < 4; ++k) {
        const int c4 = k * 256 + tid;             // float4 slot in output row
        const int4 ci = ((const int4*)idx)[c4];   // 4 kept column indices
        nfloat4 o = {Arow[ci.x], Arow[ci.y], Arow[ci.z], Arow[ci.w]};
        __builtin_nontemporal_store(o, (nfloat4*)orow + c4);
    }
}

// ---------------------------------------------------------------------------
extern "C" void kernel_launch(void* const* d_in, const int* in_sizes, int n_in,
                              void* d_out, int out_size, void* d_ws, size_t ws_size,
                              hipStream_t stream) {
    const float* X = (const float*)d_in[0];   // (8192, 256)
    const float* A = (const float*)d_in[1];   // (8192, 8192)
    const float* p = (const float*)d_in[2];   // (256, 1)

    float* ws_f   = (float*)d_ws;
    float* s_arr  = ws_f;                       // 8192 floats
    float* t_arr  = ws_f + N_ROWS;              // 8192 floats
    int*   rank_a = (int*)(ws_f + 2 * N_ROWS);  // 8192 ints
    int*   idx    = (int*)(ws_f + 3 * N_ROWS);  // 4096 ints

    float* out0 = (float*)d_out;                       // X_pooled (4096,256)
    float* out1 = out0 + (size_t)K_KEEP * F_DIM;       // A_pooled (4096,4096)

    k_scores <<<N_ROWS / 4, 256,  0, stream>>>(X, p, s_arr, t_arr, rank_a);
    k_rank   <<<32 * 16,    256,  0, stream>>>(s_arr, rank_a);
    k_compact<<<1,          1024, 0, stream>>>(rank_a, idx);
    k_pool   <<<K_KEEP,     256,  0, stream>>>(X, A, t_arr, idx, out0, out1);
}